// Round 6
// baseline (400.710 us; speedup 1.0000x reference)
//
#include <hip/hip_runtime.h>
#include <hip/hip_bf16.h>
#include <stdint.h>

typedef __bf16 bf16x8 __attribute__((ext_vector_type(8)));
typedef float f32x4 __attribute__((ext_vector_type(4)));

static __device__ __forceinline__ unsigned short f2bf(float x) {
    union { float f; unsigned u; } v; v.f = x;
    unsigned r = v.u + 0x7FFFu + ((v.u >> 16) & 1u);  // round-to-nearest-even
    return (unsigned short)(r >> 16);
}

static __device__ __forceinline__ void gload_lds16(const void* g, void* l) {
    auto gp = (const unsigned int __attribute__((address_space(1)))*)(reinterpret_cast<uintptr_t>(g));
    auto lp = (unsigned int __attribute__((address_space(3)))*)(reinterpret_cast<uintptr_t>(l));
    __builtin_amdgcn_global_load_lds(gp, lp, 16, 0, 0);
}

// ---------- Kernel A: attn = softmax(morphosyn @ W_affix), stored bf16, 16B-block XOR-swizzled ----------
__global__ void attn_kernel(const float* __restrict__ morphosyn,
                            const float* __restrict__ W,
                            unsigned short* __restrict__ attn_sw) {
    const int b = blockIdx.x;
    const int t = threadIdx.x;
    __shared__ float ms[128];
    __shared__ float red[4];
    if (t < 128) ms[t] = morphosyn[b * 128 + t];
    __syncthreads();
    float acc0 = 0.f, acc1 = 0.f;
    #pragma unroll 8
    for (int dm = 0; dm < 128; ++dm) {
        float m = ms[dm];
        acc0 = fmaf(m, W[dm * 512 + t], acc0);
        acc1 = fmaf(m, W[dm * 512 + t + 256], acc1);
    }
    const int lane = t & 63, wid = t >> 6;
    float mx = fmaxf(acc0, acc1);
    #pragma unroll
    for (int o = 32; o; o >>= 1) mx = fmaxf(mx, __shfl_xor(mx, o));
    if (lane == 0) red[wid] = mx;
    __syncthreads();
    mx = fmaxf(fmaxf(red[0], red[1]), fmaxf(red[2], red[3]));
    __syncthreads();
    float e0 = __expf(acc0 - mx), e1 = __expf(acc1 - mx);
    float sm = e0 + e1;
    #pragma unroll
    for (int o = 32; o; o >>= 1) sm += __shfl_xor(sm, o);
    if (lane == 0) red[wid] = sm;
    __syncthreads();
    sm = red[0] + red[1] + red[2] + red[3];
    const float inv = 1.0f / sm;
    const int swz = (b >> 2) & 3;
    #pragma unroll
    for (int h = 0; h < 2; ++h) {
        int v = t + h * 256;
        int ae = (v >> 5) * 32 + ((((v >> 3) & 3) ^ swz) << 3) + (v & 7);
        attn_sw[b * 512 + ae] = f2bf((h ? e1 : e0) * inv);
    }
}

// ---------- Kernel B: wC[b,n] = cumsum_n( sum_ijk a_i b_j f_k softmax(logits[ijbk,:]) ) ----------
__global__ void wc_kernel(const float* __restrict__ logits,
                          const float* __restrict__ alpha,
                          const float* __restrict__ beta,
                          const float* __restrict__ phi,
                          float* __restrict__ wC) {
    const int b = blockIdx.x;
    const int t = threadIdx.x;
    const int lane = t & 63, wid = t >> 6;
    __shared__ float part[4][256];
    __shared__ float wsum[4];

    float a0 = alpha[0], a1 = alpha[1];
    float am = fmaxf(a0, a1);
    float ea0 = __expf(a0 - am), ea1 = __expf(a1 - am);
    float as = ea0 + ea1;
    float b0 = beta[0], b1 = beta[1];
    float bm = fmaxf(b0, b1);
    float eb0 = __expf(b0 - bm), eb1 = __expf(b1 - bm);
    float bs = eb0 + eb1;
    float p[5];
    float pm = -1e30f;
    #pragma unroll
    for (int k = 0; k < 5; ++k) { p[k] = phi[k]; pm = fmaxf(pm, p[k]); }
    float ps = 0.f;
    #pragma unroll
    for (int k = 0; k < 5; ++k) { p[k] = __expf(p[k] - pm); ps += p[k]; }
    const float wa[2] = {ea0 / as, ea1 / as}, wb[2] = {eb0 / bs, eb1 / bs};

    f32x4 accv = {0.f, 0.f, 0.f, 0.f};
    #pragma unroll
    for (int s5 = 0; s5 < 5; ++s5) {
        int sl = wid * 5 + s5;
        int i = sl >= 10;
        int j = (sl / 5) & 1;
        int k = sl - (sl / 5) * 5;
        const float* base = logits + ((size_t)(((i * 2 + j) * 1024 + b) * 5 + k)) * 256;
        f32x4 x = *(const f32x4*)(base + lane * 4);
        float mx = fmaxf(fmaxf(x[0], x[1]), fmaxf(x[2], x[3]));
        #pragma unroll
        for (int o = 32; o; o >>= 1) mx = fmaxf(mx, __shfl_xor(mx, o));
        f32x4 e;
        float sm = 0.f;
        #pragma unroll
        for (int r = 0; r < 4; ++r) { e[r] = __expf(x[r] - mx); sm += e[r]; }
        #pragma unroll
        for (int o = 32; o; o >>= 1) sm += __shfl_xor(sm, o);
        float w = wa[i] * wb[j] * (p[k] / ps) / sm;
        #pragma unroll
        for (int r = 0; r < 4; ++r) accv[r] += w * e[r];
    }
    *(f32x4*)&part[wid][lane * 4] = accv;
    __syncthreads();
    float v = part[0][t] + part[1][t] + part[2][t] + part[3][t];
    #pragma unroll
    for (int o = 1; o < 64; o <<= 1) {
        float u = __shfl_up(v, o);
        if (lane >= o) v += u;
    }
    if (lane == 63) wsum[wid] = v;
    __syncthreads();
    float offv = 0.f;
    for (int w2 = 0; w2 < wid; ++w2) offv += wsum[w2];
    wC[b * 256 + t] = v + offv;
}

// ---------- Kernel T: vocab f32 [v][n'] -> bf16 Bt[n'][v], 16B-block XOR-swizzled per row ----------
__global__ void conv_kernel(const float* __restrict__ vocab, unsigned short* __restrict__ Bt) {
    const int n0 = blockIdx.x * 16;
    const int t = threadIdx.x;
    __shared__ unsigned int T[16 * 256];  // [n][v/2] dwords
    #pragma unroll
    for (int it = 0; it < 4; ++it) {
        int p = it * 256 + t;
        int v = (p >> 2) * 2;
        int col4 = p & 3;
        const float* g0 = vocab + (size_t)v * 65536 + n0 + col4 * 4;
        float4 a = *(const float4*)g0;
        float4 c = *(const float4*)(g0 + 65536);
        #pragma unroll
        for (int j = 0; j < 4; ++j) {
            int n = col4 * 4 + j;
            unsigned d = (unsigned)f2bf((&a.x)[j]) | ((unsigned)f2bf((&c.x)[j]) << 16);
            T[n * 256 + (v >> 1)] = d;
        }
    }
    __syncthreads();
    #pragma unroll
    for (int it = 0; it < 4; ++it) {
        int qq = it * 256 + t;
        int r = qq >> 6, c = qq & 63;
        int swz = ((n0 + r) >> 2) & 3;
        int dc = (c & ~3) | ((c & 3) ^ swz);
        uint4 d = *(const uint4*)(&T[r * 256 + c * 4]);
        *(uint4*)(Bt + (size_t)(n0 + r) * 512 + dc * 8) = d;
    }
}

// ---------- Kernel C (fast): 64x256 tile, BK=32, 4 waves, 2-buf, 4 blocks/CU ----------
// LDS 40KB -> 4 blocks/CU resident: 4 independent streams hide the ~900cy staging latency
// that the per-iteration __syncthreads drain exposes.
__global__ __launch_bounds__(256, 4) void gemm_kernel(
        const unsigned short* __restrict__ attn_sw,
        const unsigned short* __restrict__ Bt,
        const float* __restrict__ stem,
        const float* __restrict__ wC,
        float* __restrict__ out) {
    // 4096 blocks: xcd = bid&7; 32 n-panels/XCD x 16 m-tiles, m fastest (panel L2 reuse).
    const int bid = blockIdx.x;
    const int xcd = bid & 7, s = bid >> 3;          // s: 0..511
    const int m0 = (s & 15) << 6;                   // 16 m-tiles of 64 rows
    const int n0 = ((xcd << 5) + (s >> 4)) << 8;    // 256 n-panels of 256 cols
    const int t = threadIdx.x;                      // 0..255
    const int lane = t & 63, wid = t >> 6;          // 4 waves; wave w owns cols w*64..+63
    const int q = lane >> 4, rl = lane & 15;
    const int soff = ((q ^ ((rl >> 2) & 3)) << 4);  // XOR-swizzle byte offset (matches writers)

    __shared__ __align__(16) unsigned short ldsb[20480];  // 40KB: 2 bufs x (A 4KB + B 16KB)

    f32x4 acc[4][4];
    const f32x4 z = {0.f, 0.f, 0.f, 0.f};
    #pragma unroll
    for (int i = 0; i < 4; ++i)
        #pragma unroll
        for (int j = 0; j < 4; ++j) acc[i][j] = z;

    // per-thread staging sources (pre-swizzled in ws -> linear LDS dest is correct)
    const unsigned short* a_src = attn_sw + (size_t)(m0 + (t >> 2)) * 512 + (t & 3) * 8;
    const unsigned short* b_src = Bt + (size_t)(n0 + (t >> 2)) * 512 + (t & 3) * 8;

#define STAGE(kt) do { \
    unsigned short* dst_ = ldsb + (((kt) & 1) ? 10240 : 0); \
    const int ko_ = (kt) * 32; \
    gload_lds16(a_src + ko_, dst_ + t * 8); \
    _Pragma("unroll") \
    for (int i_ = 0; i_ < 4; ++i_) \
        gload_lds16(b_src + (size_t)i_ * 32768 + ko_, dst_ + 2048 + (i_ * 256 + t) * 8); \
} while (0)

    STAGE(0);
    __syncthreads();

    for (int kt = 0; kt < 16; ++kt) {
        if (kt < 15) STAGE(kt + 1);   // prefetch overlaps this iteration's compute
        const char* buf = (const char*)(ldsb + ((kt & 1) ? 10240 : 0));
        const char* bbase = buf + 4096;
        bf16x8 af[4], bfv[4];
        #pragma unroll
        for (int f = 0; f < 4; ++f)
            af[f] = *(const bf16x8*)(buf + (f * 16 + rl) * 64 + soff);
        #pragma unroll
        for (int j = 0; j < 4; ++j) {
            int c = wid * 64 + j * 16 + rl;
            bfv[j] = *(const bf16x8*)(bbase + c * 64 + soff);
        }
        #pragma unroll
        for (int fm = 0; fm < 4; ++fm)
            #pragma unroll
            for (int j = 0; j < 4; ++j)
                acc[fm][j] = __builtin_amdgcn_mfma_f32_16x16x32_bf16(
                    af[fm], bfv[j], acc[fm][j], 0, 0, 0);
        __syncthreads();  // drains vmcnt (prefetch landed) + all waves done reading buf
    }
#undef STAGE

    // ---- epilogue: 2 half-passes; acc -> LDS [32][260] -> full-row float4 RMW ----
    float* cs = (float*)ldsb;
    #pragma unroll
    for (int sb = 0; sb < 2; ++sb) {
        if (sb) __syncthreads();
        #pragma unroll
        for (int fh = 0; fh < 2; ++fh) {
            int f = sb * 2 + fh;
            #pragma unroll
            for (int n = 0; n < 4; ++n) {
                int c = wid * 64 + n * 16 + rl;
                #pragma unroll
                for (int i = 0; i < 4; ++i)
                    cs[(fh * 16 + q * 4 + i) * 260 + c] = acc[f][n][i];
            }
        }
        __syncthreads();
        {
            int row = t >> 3, c0 = (t & 7) * 32;   // 32 rows x 8 threads; 128B/thread
            int b = m0 + sb * 32 + row;
            size_t gb = (size_t)b * 65536 + (size_t)n0 + c0;
            const float* crow = &cs[row * 260 + c0];
            const float* wrow = &wC[((size_t)b << 8) + c0];  // n0 % 256 == 0
            #pragma unroll
            for (int v4 = 0; v4 < 8; ++v4) {
                f32x4 cv = *(const f32x4*)&crow[v4 * 4];
                f32x4 sv = *(const f32x4*)&stem[gb + v4 * 4];
                f32x4 wv = *(const f32x4*)&wrow[v4 * 4];
                f32x4 ov;
                #pragma unroll
                for (int jj = 0; jj < 4; ++jj)
                    ov[jj] = sv[jj] + (cv[jj] - sv[jj]) * wv[jj];
                *(f32x4*)&out[gb + v4 * 4] = ov;
            }
        }
    }
}

// ---------- Kernel C (fallback, ws too small): in-kernel convert+transpose, 128^2 ----------
__global__ void gemm_fb(const unsigned short* __restrict__ attn_sw,
                        const float* __restrict__ vocab,
                        const float* __restrict__ stem,
                        const float* __restrict__ wC,
                        float* __restrict__ out) {
    const int tile_m = blockIdx.x & 7;
    const int tile_n = blockIdx.x >> 3;
    const int m0 = tile_m << 7;
    const int n0 = tile_n << 7;
    const int t = threadIdx.x;
    const int lane = t & 63;
    const int wv = t >> 6;
    const int wm = wv >> 1, wn = wv & 1;

    __shared__ unsigned short Asl[128 * 32];
    __shared__ unsigned short Bsl[128 * 32];

    f32x4 acc[4][4];
    const f32x4 z = {0.f, 0.f, 0.f, 0.f};
    #pragma unroll
    for (int i = 0; i < 4; ++i)
        #pragma unroll
        for (int j = 0; j < 4; ++j) acc[i][j] = z;

    const unsigned short* a_base = attn_sw + ((size_t)m0 << 9);
    const int q = lane >> 4;
    const int rl = lane & 15;

    for (int ks = 0; ks < 16; ++ks) {
        #pragma unroll
        for (int it = 0; it < 2; ++it) {
            int idx = it * 256 + t;
            int r = idx >> 2, blk = idx & 3;
            gload_lds16(a_base + r * 512 + ks * 32 + blk * 8, Asl + idx * 8);
        }
        #pragma unroll
        for (int it = 0; it < 2; ++it) {
            int lin = it * 256 + t;
            int pair = lin >> 5;
            int chunk = lin & 31;
            int k = pair * 2;
            const float* g0 = vocab + (size_t)(ks * 32 + k) * 65536 + n0 + chunk * 4;
            float4 v0 = *(const float4*)g0;
            float4 v1 = *(const float4*)(g0 + 65536);
            #pragma unroll
            for (int j = 0; j < 4; ++j) {
                int n = chunk * 4 + j;
                unsigned d = (unsigned)f2bf((&v0.x)[j]) | ((unsigned)f2bf((&v1.x)[j]) << 16);
                int ae = n * 32 + ((((k >> 3) ^ ((n >> 2) & 3))) << 3) + (k & 7);
                *(unsigned*)((char*)Bsl + ae * 2) = d;
            }
        }
        __syncthreads();
        bf16x8 af[4], bfr[4];
        #pragma unroll
        for (int f = 0; f < 4; ++f) {
            int r = wm * 64 + f * 16 + rl;
            af[f] = *(const bf16x8*)((const char*)Asl + r * 64 + ((q ^ ((r >> 2) & 3)) << 4));
            int c = wn * 64 + f * 16 + rl;
            bfr[f] = *(const bf16x8*)((const char*)Bsl + c * 64 + ((q ^ ((c >> 2) & 3)) << 4));
        }
        __syncthreads();
        #pragma unroll
        for (int fm = 0; fm < 4; ++fm)
            #pragma unroll
            for (int fn = 0; fn < 4; ++fn)
                acc[fm][fn] = __builtin_amdgcn_mfma_f32_16x16x32_bf16(af[fm], bfr[fn], acc[fm][fn], 0, 0, 0);
    }

    #pragma unroll
    for (int fm = 0; fm < 4; ++fm) {
        int rbase = m0 + wm * 64 + fm * 16 + ((lane >> 4) << 2);
        #pragma unroll
        for (int fn = 0; fn < 4; ++fn) {
            int c = n0 + wn * 64 + fn * 16 + (lane & 15);
            #pragma unroll
            for (int i = 0; i < 4; ++i) {
                int b = rbase + i;
                float w = wC[(b << 8) + (c & 255)];
                size_t o = ((size_t)b << 16) + (size_t)c;
                float sv = stem[o];
                out[o] = sv + (acc[fm][fn][i] - sv) * w;
            }
        }
    }
}

extern "C" void kernel_launch(void* const* d_in, const int* in_sizes, int n_in,
                              void* d_out, int out_size, void* d_ws, size_t ws_size,
                              hipStream_t stream) {
    const float* stem    = (const float*)d_in[0];
    const float* morpho  = (const float*)d_in[1];
    const float* logits  = (const float*)d_in[2];
    const float* W       = (const float*)d_in[3];
    const float* vocab   = (const float*)d_in[4];
    const float* alpha   = (const float*)d_in[5];
    const float* beta    = (const float*)d_in[6];
    const float* phi     = (const float*)d_in[7];
    float* out = (float*)d_out;

    unsigned short* attn_sw = (unsigned short*)d_ws;                 // 1 MB
    float* wC = (float*)((char*)d_ws + (1 << 20));                   // 1 MB
    unsigned short* Bt = (unsigned short*)((char*)d_ws + (2 << 20)); // 64 MB

    const size_t need = (size_t)(2 << 20) + (size_t)64 * 1024 * 1024;

    attn_kernel<<<1024, 256, 0, stream>>>(morpho, W, attn_sw);
    wc_kernel<<<1024, 256, 0, stream>>>(logits, alpha, beta, phi, wC);
    if (ws_size >= need) {
        conv_kernel<<<4096, 256, 0, stream>>>(vocab, Bt);
        gemm_kernel<<<4096, 256, 0, stream>>>(attn_sw, Bt, stem, wC, out);
    } else {
        gemm_fb<<<4096, 256, 0, stream>>>(attn_sw, vocab, stem, wC, out);
    }
}

// Round 7
// 267.993 us; speedup vs baseline: 1.4952x; 1.4952x over previous
//
#include <hip/hip_runtime.h>
#include <hip/hip_bf16.h>
#include <stdint.h>

typedef __bf16 bf16x8 __attribute__((ext_vector_type(8)));
typedef float f32x4 __attribute__((ext_vector_type(4)));

static __device__ __forceinline__ unsigned short f2bf(float x) {
    union { float f; unsigned u; } v; v.f = x;
    unsigned r = v.u + 0x7FFFu + ((v.u >> 16) & 1u);  // round-to-nearest-even
    return (unsigned short)(r >> 16);
}

static __device__ __forceinline__ void gload_lds16(const void* g, void* l) {
    auto gp = (const unsigned int __attribute__((address_space(1)))*)(reinterpret_cast<uintptr_t>(g));
    auto lp = (unsigned int __attribute__((address_space(3)))*)(reinterpret_cast<uintptr_t>(l));
    __builtin_amdgcn_global_load_lds(gp, lp, 16, 0, 0);
}

// ---------- Kernel A: attn = softmax(morphosyn @ W_affix), stored bf16, 16B-block XOR-swizzled ----------
__global__ void attn_kernel(const float* __restrict__ morphosyn,
                            const float* __restrict__ W,
                            unsigned short* __restrict__ attn_sw) {
    const int b = blockIdx.x;
    const int t = threadIdx.x;
    __shared__ float ms[128];
    __shared__ float red[4];
    if (t < 128) ms[t] = morphosyn[b * 128 + t];
    __syncthreads();
    float acc0 = 0.f, acc1 = 0.f;
    #pragma unroll 8
    for (int dm = 0; dm < 128; ++dm) {
        float m = ms[dm];
        acc0 = fmaf(m, W[dm * 512 + t], acc0);
        acc1 = fmaf(m, W[dm * 512 + t + 256], acc1);
    }
    const int lane = t & 63, wid = t >> 6;
    float mx = fmaxf(acc0, acc1);
    #pragma unroll
    for (int o = 32; o; o >>= 1) mx = fmaxf(mx, __shfl_xor(mx, o));
    if (lane == 0) red[wid] = mx;
    __syncthreads();
    mx = fmaxf(fmaxf(red[0], red[1]), fmaxf(red[2], red[3]));
    __syncthreads();
    float e0 = __expf(acc0 - mx), e1 = __expf(acc1 - mx);
    float sm = e0 + e1;
    #pragma unroll
    for (int o = 32; o; o >>= 1) sm += __shfl_xor(sm, o);
    if (lane == 0) red[wid] = sm;
    __syncthreads();
    sm = red[0] + red[1] + red[2] + red[3];
    const float inv = 1.0f / sm;
    const int swz = (b >> 2) & 3;
    #pragma unroll
    for (int h = 0; h < 2; ++h) {
        int v = t + h * 256;
        int ae = (v >> 5) * 32 + ((((v >> 3) & 3) ^ swz) << 3) + (v & 7);
        attn_sw[b * 512 + ae] = f2bf((h ? e1 : e0) * inv);
    }
}

// ---------- Kernel B: wC[b,n] = cumsum_n( sum_ijk a_i b_j f_k softmax(logits[ijbk,:]) ) ----------
__global__ void wc_kernel(const float* __restrict__ logits,
                          const float* __restrict__ alpha,
                          const float* __restrict__ beta,
                          const float* __restrict__ phi,
                          float* __restrict__ wC) {
    const int b = blockIdx.x;
    const int t = threadIdx.x;
    const int lane = t & 63, wid = t >> 6;
    __shared__ float part[4][256];
    __shared__ float wsum[4];

    float a0 = alpha[0], a1 = alpha[1];
    float am = fmaxf(a0, a1);
    float ea0 = __expf(a0 - am), ea1 = __expf(a1 - am);
    float as = ea0 + ea1;
    float b0 = beta[0], b1 = beta[1];
    float bm = fmaxf(b0, b1);
    float eb0 = __expf(b0 - bm), eb1 = __expf(b1 - bm);
    float bs = eb0 + eb1;
    float p[5];
    float pm = -1e30f;
    #pragma unroll
    for (int k = 0; k < 5; ++k) { p[k] = phi[k]; pm = fmaxf(pm, p[k]); }
    float ps = 0.f;
    #pragma unroll
    for (int k = 0; k < 5; ++k) { p[k] = __expf(p[k] - pm); ps += p[k]; }
    const float wa[2] = {ea0 / as, ea1 / as}, wb[2] = {eb0 / bs, eb1 / bs};

    f32x4 accv = {0.f, 0.f, 0.f, 0.f};
    #pragma unroll
    for (int s5 = 0; s5 < 5; ++s5) {
        int sl = wid * 5 + s5;
        int i = sl >= 10;
        int j = (sl / 5) & 1;
        int k = sl - (sl / 5) * 5;
        const float* base = logits + ((size_t)(((i * 2 + j) * 1024 + b) * 5 + k)) * 256;
        f32x4 x = *(const f32x4*)(base + lane * 4);
        float mx = fmaxf(fmaxf(x[0], x[1]), fmaxf(x[2], x[3]));
        #pragma unroll
        for (int o = 32; o; o >>= 1) mx = fmaxf(mx, __shfl_xor(mx, o));
        f32x4 e;
        float sm = 0.f;
        #pragma unroll
        for (int r = 0; r < 4; ++r) { e[r] = __expf(x[r] - mx); sm += e[r]; }
        #pragma unroll
        for (int o = 32; o; o >>= 1) sm += __shfl_xor(sm, o);
        float w = wa[i] * wb[j] * (p[k] / ps) / sm;
        #pragma unroll
        for (int r = 0; r < 4; ++r) accv[r] += w * e[r];
    }
    *(f32x4*)&part[wid][lane * 4] = accv;
    __syncthreads();
    float v = part[0][t] + part[1][t] + part[2][t] + part[3][t];
    #pragma unroll
    for (int o = 1; o < 64; o <<= 1) {
        float u = __shfl_up(v, o);
        if (lane >= o) v += u;
    }
    if (lane == 63) wsum[wid] = v;
    __syncthreads();
    float offv = 0.f;
    for (int w2 = 0; w2 < wid; ++w2) offv += wsum[w2];
    wC[b * 256 + t] = v + offv;
}

// ---------- Kernel T: vocab f32 [v][n'] -> bf16 Bt[n'][v], 16B-block XOR-swizzled per row ----------
__global__ void conv_kernel(const float* __restrict__ vocab, unsigned short* __restrict__ Bt) {
    const int n0 = blockIdx.x * 16;
    const int t = threadIdx.x;
    __shared__ unsigned int T[16 * 256];  // [n][v/2] dwords
    #pragma unroll
    for (int it = 0; it < 4; ++it) {
        int p = it * 256 + t;
        int v = (p >> 2) * 2;
        int col4 = p & 3;
        const float* g0 = vocab + (size_t)v * 65536 + n0 + col4 * 4;
        float4 a = *(const float4*)g0;
        float4 c = *(const float4*)(g0 + 65536);
        #pragma unroll
        for (int j = 0; j < 4; ++j) {
            int n = col4 * 4 + j;
            unsigned d = (unsigned)f2bf((&a.x)[j]) | ((unsigned)f2bf((&c.x)[j]) << 16);
            T[n * 256 + (v >> 1)] = d;
        }
    }
    __syncthreads();
    #pragma unroll
    for (int it = 0; it < 4; ++it) {
        int qq = it * 256 + t;
        int r = qq >> 6, c = qq & 63;
        int swz = ((n0 + r) >> 2) & 3;
        int dc = (c & ~3) | ((c & 3) ^ swz);
        uint4 d = *(const uint4*)(&T[r * 256 + c * 4]);
        *(uint4*)(Bt + (size_t)(n0 + r) * 512 + dc * 8) = d;
    }
}

// ---------- Kernel C (fast): 64x512 tile, BK=32, 4 waves, 2-buf, counted-vmcnt pipeline ----------
// R5 geometry (verified absmax 0.0156, clean 484MB traffic) with T4 counted vmcnt:
// stage(kt+1) stays in flight across the whole iteration; wait vmcnt(9) instead of drain-0.
__global__ __launch_bounds__(256, 2) void gemm_kernel(
        const unsigned short* __restrict__ attn_sw,
        const unsigned short* __restrict__ Bt,
        const float* __restrict__ stem,
        const float* __restrict__ wC,
        float* __restrict__ out) {
    // 2048 blocks: xcd = bid&7; 16 panels/XCD; 16 m-tiles of one panel consecutive on one XCD.
    const int bid = blockIdx.x;
    const int xcd = bid & 7, s = bid >> 3;          // s: 0..255
    const int m0 = (s & 15) << 6;                   // 16 m-tiles of 64 rows
    const int n0 = ((xcd << 4) + (s >> 4)) << 9;    // 128 n-panels of 512 cols
    const int t = threadIdx.x;                      // 0..255
    const int lane = t & 63, wid = t >> 6;          // 4 waves; wave w owns cols w*128..+127
    const int q = lane >> 4, rl = lane & 15;
    const int soff = ((q ^ ((rl >> 2) & 3)) << 4);  // XOR-swizzle byte offset (matches writers)

    __shared__ __align__(16) unsigned short ldsb[36864];  // 72KB: 2 bufs x (A 4KB + B 32KB)

    f32x4 acc[4][8];
    const f32x4 z = {0.f, 0.f, 0.f, 0.f};
    #pragma unroll
    for (int i = 0; i < 4; ++i)
        #pragma unroll
        for (int j = 0; j < 8; ++j) acc[i][j] = z;

    // per-thread staging sources (pre-swizzled in ws -> linear LDS dest is correct)
    const unsigned short* a_src = attn_sw + (size_t)(m0 + (t >> 2)) * 512 + (t & 3) * 8;
    const unsigned short* b_src = Bt + (size_t)(n0 + (t >> 2)) * 512 + (t & 3) * 8;

// 9 global_load_lds per thread (1 A + 8 B)
#define STAGE(kt) do { \
    unsigned short* dst_ = ldsb + (((kt) & 1) ? 18432 : 0); \
    const int ko_ = (kt) * 32; \
    gload_lds16(a_src + ko_, dst_ + t * 8); \
    _Pragma("unroll") \
    for (int i_ = 0; i_ < 8; ++i_) \
        gload_lds16(b_src + (size_t)i_ * 32768 + ko_, dst_ + 2048 + (i_ * 256 + t) * 8); \
} while (0)

// One K-step. STG=1: issue next-tile prefetch; VMSTR: outstanding loads allowed
// ("9" = the 9 just-issued for kt+1; stage(kt) fully landed).
#define KSTEP(kt, STG, VMSTR) do { \
    if (STG) STAGE((kt) + 1); \
    asm volatile("s_waitcnt vmcnt(" VMSTR ")" ::: "memory"); \
    __builtin_amdgcn_s_barrier(); \
    __builtin_amdgcn_sched_barrier(0); \
    const char* buf_ = (const char*)(ldsb + (((kt) & 1) ? 18432 : 0)); \
    const char* bbase_ = buf_ + 4096; \
    bf16x8 af_[4]; \
    _Pragma("unroll") \
    for (int f_ = 0; f_ < 4; ++f_) \
        af_[f_] = *(const bf16x8*)(buf_ + (f_ * 16 + rl) * 64 + soff); \
    _Pragma("unroll") \
    for (int h_ = 0; h_ < 2; ++h_) { \
        bf16x8 bfv_[4]; \
        _Pragma("unroll") \
        for (int j_ = 0; j_ < 4; ++j_) { \
            int c_ = wid * 128 + (h_ * 4 + j_) * 16 + rl; \
            bfv_[j_] = *(const bf16x8*)(bbase_ + c_ * 64 + soff); \
        } \
        _Pragma("unroll") \
        for (int fm_ = 0; fm_ < 4; ++fm_) \
            _Pragma("unroll") \
            for (int j_ = 0; j_ < 4; ++j_) \
                acc[fm_][h_ * 4 + j_] = __builtin_amdgcn_mfma_f32_16x16x32_bf16( \
                    af_[fm_], bfv_[j_], acc[fm_][h_ * 4 + j_], 0, 0, 0); \
    } \
    __builtin_amdgcn_sched_barrier(0); \
    __builtin_amdgcn_s_barrier(); \
} while (0)

    STAGE(0);
    KSTEP(0, 1, "9");  KSTEP(1, 1, "9");  KSTEP(2, 1, "9");  KSTEP(3, 1, "9");
    KSTEP(4, 1, "9");  KSTEP(5, 1, "9");  KSTEP(6, 1, "9");  KSTEP(7, 1, "9");
    KSTEP(8, 1, "9");  KSTEP(9, 1, "9");  KSTEP(10, 1, "9"); KSTEP(11, 1, "9");
    KSTEP(12, 1, "9"); KSTEP(13, 1, "9"); KSTEP(14, 1, "9"); KSTEP(15, 0, "0");
#undef STAGE
#undef KSTEP
    __syncthreads();  // full fence before LDS reuse by epilogue

    // ---- epilogue: 2 half-passes; acc -> LDS [32][516] -> full-row float4 RMW ----
    float* cs = (float*)ldsb;
    #pragma unroll
    for (int sb = 0; sb < 2; ++sb) {
        if (sb) __syncthreads();
        #pragma unroll
        for (int fh = 0; fh < 2; ++fh) {
            int f = sb * 2 + fh;
            #pragma unroll
            for (int n = 0; n < 8; ++n) {
                int c = wid * 128 + n * 16 + rl;
                #pragma unroll
                for (int i = 0; i < 4; ++i)
                    cs[(fh * 16 + q * 4 + i) * 516 + c] = acc[f][n][i];
            }
        }
        __syncthreads();
        #pragma unroll
        for (int i = 0; i < 8; ++i) {
            int row = wid * 8 + i;                 // 0..31 within half-pass
            int b = m0 + sb * 32 + row;
            size_t gb = (size_t)b * 65536 + (size_t)n0;
            f32x4 wv = *(const f32x4*)&wC[((size_t)b << 8) + lane * 4];  // n0%256==0
            #pragma unroll
            for (int half = 0; half < 2; ++half) {
                int c = half * 256 + lane * 4;     // wave covers 1KB contiguous per instr
                f32x4 cv = *(const f32x4*)&cs[row * 516 + c];
                f32x4 sv = *(const f32x4*)&stem[gb + c];
                f32x4 ov;
                #pragma unroll
                for (int jj = 0; jj < 4; ++jj)
                    ov[jj] = sv[jj] + (cv[jj] - sv[jj]) * wv[jj];
                *(f32x4*)&out[gb + c] = ov;
            }
        }
    }
}

// ---------- Kernel C (fallback, ws too small): in-kernel convert+transpose, 128^2 ----------
__global__ void gemm_fb(const unsigned short* __restrict__ attn_sw,
                        const float* __restrict__ vocab,
                        const float* __restrict__ stem,
                        const float* __restrict__ wC,
                        float* __restrict__ out) {
    const int tile_m = blockIdx.x & 7;
    const int tile_n = blockIdx.x >> 3;
    const int m0 = tile_m << 7;
    const int n0 = tile_n << 7;
    const int t = threadIdx.x;
    const int lane = t & 63;
    const int wv = t >> 6;
    const int wm = wv >> 1, wn = wv & 1;

    __shared__ unsigned short Asl[128 * 32];
    __shared__ unsigned short Bsl[128 * 32];

    f32x4 acc[4][4];
    const f32x4 z = {0.f, 0.f, 0.f, 0.f};
    #pragma unroll
    for (int i = 0; i < 4; ++i)
        #pragma unroll
        for (int j = 0; j < 4; ++j) acc[i][j] = z;

    const unsigned short* a_base = attn_sw + ((size_t)m0 << 9);
    const int q = lane >> 4;
    const int rl = lane & 15;

    for (int ks = 0; ks < 16; ++ks) {
        #pragma unroll
        for (int it = 0; it < 2; ++it) {
            int idx = it * 256 + t;
            int r = idx >> 2, blk = idx & 3;
            gload_lds16(a_base + r * 512 + ks * 32 + blk * 8, Asl + idx * 8);
        }
        #pragma unroll
        for (int it = 0; it < 2; ++it) {
            int lin = it * 256 + t;
            int pair = lin >> 5;
            int chunk = lin & 31;
            int k = pair * 2;
            const float* g0 = vocab + (size_t)(ks * 32 + k) * 65536 + n0 + chunk * 4;
            float4 v0 = *(const float4*)g0;
            float4 v1 = *(const float4*)(g0 + 65536);
            #pragma unroll
            for (int j = 0; j < 4; ++j) {
                int n = chunk * 4 + j;
                unsigned d = (unsigned)f2bf((&v0.x)[j]) | ((unsigned)f2bf((&v1.x)[j]) << 16);
                int ae = n * 32 + ((((k >> 3) ^ ((n >> 2) & 3))) << 3) + (k & 7);
                *(unsigned*)((char*)Bsl + ae * 2) = d;
            }
        }
        __syncthreads();
        bf16x8 af[4], bfr[4];
        #pragma unroll
        for (int f = 0; f < 4; ++f) {
            int r = wm * 64 + f * 16 + rl;
            af[f] = *(const bf16x8*)((const char*)Asl + r * 64 + ((q ^ ((r >> 2) & 3)) << 4));
            int c = wn * 64 + f * 16 + rl;
            bfr[f] = *(const bf16x8*)((const char*)Bsl + c * 64 + ((q ^ ((c >> 2) & 3)) << 4));
        }
        __syncthreads();
        #pragma unroll
        for (int fm = 0; fm < 4; ++fm)
            #pragma unroll
            for (int fn = 0; fn < 4; ++fn)
                acc[fm][fn] = __builtin_amdgcn_mfma_f32_16x16x32_bf16(af[fm], bfr[fn], acc[fm][fn], 0, 0, 0);
    }

    #pragma unroll
    for (int fm = 0; fm < 4; ++fm) {
        int rbase = m0 + wm * 64 + fm * 16 + ((lane >> 4) << 2);
        #pragma unroll
        for (int fn = 0; fn < 4; ++fn) {
            int c = n0 + wn * 64 + fn * 16 + (lane & 15);
            #pragma unroll
            for (int i = 0; i < 4; ++i) {
                int b = rbase + i;
                float w = wC[(b << 8) + (c & 255)];
                size_t o = ((size_t)b << 16) + (size_t)c;
                float sv = stem[o];
                out[o] = sv + (acc[fm][fn][i] - sv) * w;
            }
        }
    }
}

extern "C" void kernel_launch(void* const* d_in, const int* in_sizes, int n_in,
                              void* d_out, int out_size, void* d_ws, size_t ws_size,
                              hipStream_t stream) {
    const float* stem    = (const float*)d_in[0];
    const float* morpho  = (const float*)d_in[1];
    const float* logits  = (const float*)d_in[2];
    const float* W       = (const float*)d_in[3];
    const float* vocab   = (const float*)d_in[4];
    const float* alpha   = (const float*)d_in[5];
    const float* beta    = (const float*)d_in[6];
    const float* phi     = (const float*)d_in[7];
    float* out = (float*)d_out;

    unsigned short* attn_sw = (unsigned short*)d_ws;                 // 1 MB
    float* wC = (float*)((char*)d_ws + (1 << 20));                   // 1 MB
    unsigned short* Bt = (unsigned short*)((char*)d_ws + (2 << 20)); // 64 MB

    const size_t need = (size_t)(2 << 20) + (size_t)64 * 1024 * 1024;

    attn_kernel<<<1024, 256, 0, stream>>>(morpho, W, attn_sw);
    wc_kernel<<<1024, 256, 0, stream>>>(logits, alpha, beta, phi, wC);
    if (ws_size >= need) {
        conv_kernel<<<4096, 256, 0, stream>>>(vocab, Bt);
        gemm_kernel<<<2048, 256, 0, stream>>>(attn_sw, Bt, stem, wC, out);
    } else {
        gemm_fb<<<4096, 256, 0, stream>>>(attn_sw, vocab, stem, wC, out);
    }
}